// Round 10
// baseline (205.292 us; speedup 1.0000x reference)
//
#include <hip/hip_runtime.h>
#include <hip/hip_fp16.h>
#include <cmath>

#define IH 128
#define IW 128
#define NB 8

typedef __attribute__((ext_vector_type(8))) _Float16 f16x8;
typedef __attribute__((ext_vector_type(4))) float f32x4;

union U4H8 { uint4 u; f16x8 h; __half2 h2[4]; };

// ws layout (float slots):
//   xT    : [NB][IH][IW][64] fp16     = 4194304 float slots
//   wt_dc : [9][64][64] fp16 (k,o,c)  = 18432 float slots
//   wt_om : [9][32][64] fp16 (k,o,c)  = 9216  float slots
#define XT_OFF   0
#define WTDC_OFF 4194304
#define WTOM_OFF (4194304 + 18432)

// ---------------------------------------------------------------------------
// Kernel 0 (merged prep): blocks [0,2048) transpose x NCHW f32 -> NHWC fp16;
// blocks [2048,2056) convert weights to fp16 [k][o][c].
// ---------------------------------------------------------------------------
__global__ __launch_bounds__(256) void prep(
        const float* __restrict__ x,
        const float* __restrict__ w_dc,
        const float* __restrict__ w_om,
        __half* __restrict__ xT,
        __half* __restrict__ wt_dc16,
        __half* __restrict__ wt_om16) {
    const int tid = threadIdx.x;
    const int blk = blockIdx.x;
    if (blk < 2048) {
        __shared__ float t[64 * 65];
        const int b = blk >> 8;
        const int rem = blk & 255;
        const int h = rem >> 1;
        const int w0 = (rem & 1) << 6;
        for (int i = tid; i < 4096; i += 256) {
            const int c = i >> 6;
            const int w = i & 63;
            t[w * 65 + c] = x[(((size_t)(b * 64 + c)) << 14) + (h << 7) + w0 + w];
        }
        __syncthreads();
        const int c2 = (tid & 31) * 2;
        __half2* dst = (__half2*)(xT + (((size_t)b << 20)) + ((size_t)((h << 7) + w0)) * 64 + c2);
#pragma unroll
        for (int p = 0; p < 8; ++p) {
            const int w = (tid >> 5) + p * 8;
            dst[(size_t)w * 32] = __floats2half2_rn(t[w * 65 + c2], t[w * 65 + c2 + 1]);
        }
    } else {
        const int base = (blk - 2048) * 256 + tid;
        for (int idx = base; idx < 9 * 64 * 64; idx += 2048) {
            const int k = idx >> 12, o = (idx >> 6) & 63, c = idx & 63;
            wt_dc16[idx] = __float2half_rn(w_dc[(o * 64 + c) * 9 + k]);
        }
        for (int idx = base; idx < 9 * 32 * 64; idx += 2048) {
            const int k = idx >> 11, o = (idx >> 6) & 31, c = idx & 63;
            wt_om16[idx] = (o < 27) ? __float2half_rn(w_om[(o * 64 + c) * 9 + k])
                                    : __float2half_rn(0.0f);
        }
    }
}

// ---------------------------------------------------------------------------
// FUSED kernel: conv3x3->offset/mask (fp16 MFMA) -> LDS -> deform (fp16 MFMA).
// Block = 64-px strip, 4 waves x (16px x all-o). Weights per-k double-buffered
// in LDS (2x8 KB); offsets live in LDS. Gather uses packed __hfma2 blend and
// its half2 registers ARE the A-fragments (no repack).
// ---------------------------------------------------------------------------
__global__ __launch_bounds__(256, 4) void fused_dcn(
        const __half* __restrict__ xT,
        const float* __restrict__ b_om,
        const __half* __restrict__ wt_om16,  // [9][32][64]
        const float* __restrict__ b_dc,
        const __half* __restrict__ wt_dc16,  // [9][64][64]
        float* __restrict__ out) {
    __shared__ __align__(16) __half wk[2][8 * 64 * 8];   // 2 x 8192 B
    __shared__ __align__(16) float offs[27 * 68];        // 7344 B

    const int tid = threadIdx.x;
    const int b = blockIdx.x >> 8;
    const int rem = blockIdx.x & 255;
    const int h = rem >> 1;
    const int w0 = (rem & 1) << 6;
    const int wid = tid >> 6;
    const int lane = tid & 63;
    const int ln15 = lane & 15;
    const int quad = lane >> 4;
    const int lpx = (wid << 4) + ln15;

    const __half* xb = xT + ((size_t)b << 20);

    // ---------------- phase 1: offset/mask conv ----------------
    {   // stage om k=0: 256 uint4, layout s = p*32+o
        const int p = tid >> 5, o = tid & 31;
        ((uint4*)wk[0])[tid] = ((const uint4*)wt_om16)[(o << 3) + p];
    }
    __syncthreads();

    {
        f32x4 acc[2] = {{0.f, 0.f, 0.f, 0.f}, {0.f, 0.f, 0.f, 0.f}};
#pragma unroll
        for (int k = 0; k < 9; ++k) {
            if (k < 8) {   // stage next slice into other buffer
                const int p = tid >> 5, o = tid & 31;
                ((uint4*)wk[(k & 1) ^ 1])[tid] =
                    ((const uint4*)wt_om16)[((k + 1) << 8) + (o << 3) + p];
            }
            const int kh = k / 3;
            const int kw = k - kh * 3;
            const int y = h + kh - 1;
            const int xx = w0 + lpx + kw - 1;
            U4H8 a0, a1;
            a0.u = make_uint4(0u, 0u, 0u, 0u);
            a1.u = make_uint4(0u, 0u, 0u, 0u);
            if (y >= 0 && y < IH && xx >= 0 && xx < IW) {
                const __half* p = xb + (((size_t)((y << 7) + xx)) << 6) + (quad << 3);
                a0.u = *(const uint4*)p;
                a1.u = *(const uint4*)(p + 32);
            }
            const __half* wb = wk[k & 1];
#pragma unroll
            for (int ot = 0; ot < 2; ++ot) {
                U4H8 b0, b1;
                b0.u = *(const uint4*)&wb[((quad << 5) + (ot << 4) + ln15) << 3];
                b1.u = *(const uint4*)&wb[(((quad + 4) << 5) + (ot << 4) + ln15) << 3];
                acc[ot] = __builtin_amdgcn_mfma_f32_16x16x32_f16(a0.h, b0.h, acc[ot], 0, 0, 0);
                acc[ot] = __builtin_amdgcn_mfma_f32_16x16x32_f16(a1.h, b1.h, acc[ot], 0, 0, 0);
            }
            if (k < 8) __syncthreads();
        }
        // epilogue to offs[o][68]: col(o)=ln15+16ot, row(px)=quad*4+reg
#pragma unroll
        for (int ot = 0; ot < 2; ++ot) {
            const int o = (ot << 4) + ln15;
            if (o < 27) {
                const float bias = b_om[o];
                float4 r;
                r.x = acc[ot][0] + bias;
                r.y = acc[ot][1] + bias;
                r.z = acc[ot][2] + bias;
                r.w = acc[ot][3] + bias;
                if (o >= 18) {
                    r.x = 2.0f / (1.0f + __expf(-r.x));
                    r.y = 2.0f / (1.0f + __expf(-r.y));
                    r.z = 2.0f / (1.0f + __expf(-r.z));
                    r.w = 2.0f / (1.0f + __expf(-r.w));
                }
                *(float4*)&offs[o * 68 + (wid << 4) + (quad << 2)] = r;
            }
        }
    }
    __syncthreads();   // offs complete + all phase-1 wk reads done

    // ---------------- phase 2: deformable conv ----------------
    for (int s = tid; s < 512; s += 256) {   // stage dc k=0: s = p*64+o
        const int p = s >> 6, o = s & 63;
        ((uint4*)wk[0])[s] = ((const uint4*)wt_dc16)[(o << 3) + p];
    }
    __syncthreads();

    f32x4 acc[4];
#pragma unroll
    for (int i = 0; i < 4; ++i) acc[i] = (f32x4){0.f, 0.f, 0.f, 0.f};

#pragma unroll
    for (int k = 0; k < 9; ++k) {
        if (k < 8) {   // stage next dc slice into other buffer
            for (int s = tid; s < 512; s += 256) {
                const int p = s >> 6, o = s & 63;
                ((uint4*)wk[(k & 1) ^ 1])[s] =
                    ((const uint4*)wt_dc16)[((k + 1) << 9) + (o << 3) + p];
            }
        }
        const float offy = offs[(2 * k) * 68 + lpx];
        const float offx = offs[(2 * k + 1) * 68 + lpx];
        const float msk  = offs[(18 + k) * 68 + lpx];
        const int kh = k / 3;
        const int kw = k - kh * 3;
        const float py  = (float)(h + kh - 1) + offy;
        const float pxf = (float)(w0 + lpx + kw - 1) + offx;
        const float y0f = floorf(py);
        const float x0f = floorf(pxf);
        const float fy = py - y0f;
        const float fx = pxf - x0f;
        const float wy0 = 1.0f - fy, wx0 = 1.0f - fx;
        const float vy0 = (y0f >= 0.0f && y0f <= 127.0f) ? 1.0f : 0.0f;
        const float vy1 = (y0f >= -1.0f && y0f <= 126.0f) ? 1.0f : 0.0f;
        const float vx0 = (x0f >= 0.0f && x0f <= 127.0f) ? 1.0f : 0.0f;
        const float vx1 = (x0f >= -1.0f && x0f <= 126.0f) ? 1.0f : 0.0f;
        // fold mask into the bilinear weights (broadcast to half2)
        const __half2 W00 = __float2half2_rn(wy0 * wx0 * vy0 * vx0 * msk);
        const __half2 W01 = __float2half2_rn(wy0 * fx  * vy0 * vx1 * msk);
        const __half2 W10 = __float2half2_rn(fy  * wx0 * vy1 * vx0 * msk);
        const __half2 W11 = __float2half2_rn(fy  * fx  * vy1 * vx1 * msk);
        const int y0i = min(max((int)y0f, 0), 127);
        const int y1i = min(max((int)y0f + 1, 0), 127);
        const int x0i = min(max((int)x0f, 0), 127);
        const int x1i = min(max((int)x0f + 1, 0), 127);

        const __half2 hz = __float2half2_rn(0.0f);
        __half2 v[8] = {hz, hz, hz, hz, hz, hz, hz, hz};
        const int cofs = quad << 3;
        {
            const __half* p = xb + (((size_t)((y0i << 7) + x0i)) << 6) + cofs;
            U4H8 ca, cb; ca.u = *(const uint4*)p; cb.u = *(const uint4*)(p + 32);
#pragma unroll
            for (int i = 0; i < 4; ++i) { v[i] = __hfma2(ca.h2[i], W00, v[i]); v[4 + i] = __hfma2(cb.h2[i], W00, v[4 + i]); }
        }
        {
            const __half* p = xb + (((size_t)((y0i << 7) + x1i)) << 6) + cofs;
            U4H8 ca, cb; ca.u = *(const uint4*)p; cb.u = *(const uint4*)(p + 32);
#pragma unroll
            for (int i = 0; i < 4; ++i) { v[i] = __hfma2(ca.h2[i], W01, v[i]); v[4 + i] = __hfma2(cb.h2[i], W01, v[4 + i]); }
        }
        {
            const __half* p = xb + (((size_t)((y1i << 7) + x0i)) << 6) + cofs;
            U4H8 ca, cb; ca.u = *(const uint4*)p; cb.u = *(const uint4*)(p + 32);
#pragma unroll
            for (int i = 0; i < 4; ++i) { v[i] = __hfma2(ca.h2[i], W10, v[i]); v[4 + i] = __hfma2(cb.h2[i], W10, v[4 + i]); }
        }
        {
            const __half* p = xb + (((size_t)((y1i << 7) + x1i)) << 6) + cofs;
            U4H8 ca, cb; ca.u = *(const uint4*)p; cb.u = *(const uint4*)(p + 32);
#pragma unroll
            for (int i = 0; i < 4; ++i) { v[i] = __hfma2(ca.h2[i], W11, v[i]); v[4 + i] = __hfma2(cb.h2[i], W11, v[4 + i]); }
        }

        U4H8 a0, a1;
#pragma unroll
        for (int i = 0; i < 4; ++i) { a0.h2[i] = v[i]; a1.h2[i] = v[4 + i]; }

        const __half* wb = wk[k & 1];
#pragma unroll
        for (int ot = 0; ot < 4; ++ot) {
            U4H8 b0, b1;
            b0.u = *(const uint4*)&wb[((quad << 6) + (ot << 4) + ln15) << 3];
            b1.u = *(const uint4*)&wb[(((quad + 4) << 6) + (ot << 4) + ln15) << 3];
            acc[ot] = __builtin_amdgcn_mfma_f32_16x16x32_f16(a0.h, b0.h, acc[ot], 0, 0, 0);
            acc[ot] = __builtin_amdgcn_mfma_f32_16x16x32_f16(a1.h, b1.h, acc[ot], 0, 0, 0);
        }
        if (k < 8) __syncthreads();
    }

    // epilogue: col(o)=lane&15, row(px)=quad*4+reg
#pragma unroll
    for (int ot = 0; ot < 4; ++ot) {
        const int o = (ot << 4) + ln15;
        const float bias = b_dc[o];
        float4 r;
        r.x = acc[ot][0] + bias;
        r.y = acc[ot][1] + bias;
        r.z = acc[ot][2] + bias;
        r.w = acc[ot][3] + bias;
        *(float4*)&out[(((size_t)(b * 64 + o)) << 14) + (h << 7) + w0 + (wid << 4) + (quad << 2)] = r;
    }
}

extern "C" void kernel_launch(void* const* d_in, const int* in_sizes, int n_in,
                              void* d_out, int out_size, void* d_ws, size_t ws_size,
                              hipStream_t stream) {
    const float* x    = (const float*)d_in[0];
    const float* w_om = (const float*)d_in[1];
    const float* b_om = (const float*)d_in[2];
    const float* w_dc = (const float*)d_in[3];
    const float* b_dc = (const float*)d_in[4];
    float* out = (float*)d_out;
    float* ws  = (float*)d_ws;

    __half* xT      = (__half*)(ws + XT_OFF);
    __half* wt_dc16 = (__half*)(ws + WTDC_OFF);
    __half* wt_om16 = (__half*)(ws + WTOM_OFF);

    // 64-px strips: NB*IH*(IW/64) = 2048 blocks; prep adds 8 weight blocks
    prep<<<2056, 256, 0, stream>>>(x, w_dc, w_om, xT, wt_dc16, wt_om16);
    fused_dcn<<<NB * IH * (IW / 64), 256, 0, stream>>>(xT, b_om, wt_om16, b_dc, wt_dc16, out);
}